// Round 1
// baseline (362.542 us; speedup 1.0000x reference)
//
#include <hip/hip_runtime.h>
#include <math.h>

// LatentGraphNetwork: out = LN(GELU(x @ W_eff + b_eff) @ W_out + b_out)
//   W_eff = W_upd[:128] + (W_msg@graph)@W_upd[128:]   (precomputed per launch)
//   b_eff = b_upd + (b_msg@graph)@W_upd[128:]
// B=64, T=4096, D=128 -> 262144 rows of 128 fp32.

#define D 128
#define NROWS (64 * 4096)

typedef __bf16 bf16x8 __attribute__((ext_vector_type(8)));
typedef float  f32x4  __attribute__((ext_vector_type(4)));

// ---------------- prelude 1: G2 = W_msg@graph, b2tmp = b_msg@graph, W2t = W_out^T (bf16)
__global__ void prep1(const float* __restrict__ W_msg, const float* __restrict__ graph,
                      const float* __restrict__ b_msg, const float* __restrict__ W_out,
                      float* __restrict__ G2, float* __restrict__ b2tmp,
                      __bf16* __restrict__ W2t) {
    const int i = blockIdx.x;   // 0..127
    const int g = threadIdx.x;  // 0..127
    float s = 0.f;
    for (int h = 0; h < D; ++h) s += W_msg[i * D + h] * graph[h * D + g];
    G2[i * D + g] = s;
    // W2t[o2][o] = W_out[o][o2]  (o = i, o2 = g)
    W2t[g * D + i] = (__bf16)W_out[i * D + g];
    if (i == 0) {
        float sb = 0.f;
        for (int h = 0; h < D; ++h) sb += b_msg[h] * graph[h * D + g];
        b2tmp[g] = sb;
    }
}

// ---------------- prelude 2: W1t = W_eff^T (bf16), b_eff
__global__ void prep2(const float* __restrict__ W_upd, const float* __restrict__ b_upd,
                      const float* __restrict__ G2, const float* __restrict__ b2tmp,
                      __bf16* __restrict__ W1t, float* __restrict__ b_eff) {
    const int i = blockIdx.x;   // input dim 0..127
    const int o = threadIdx.x;  // output dim 0..127
    float s = W_upd[i * D + o];
    for (int g = 0; g < D; ++g) s += G2[i * D + g] * W_upd[(D + g) * D + o];
    W1t[o * D + i] = (__bf16)s;  // [n][k] layout for B-fragments
    if (i == 0) {
        float sb = b_upd[o];
        for (int g = 0; g < D; ++g) sb += b2tmp[g] * W_upd[(D + g) * D + o];
        b_eff[o] = sb;
    }
}

// ---------------- fused main: per wave, 16 rows end-to-end
__global__ __launch_bounds__(256) void fused_main(
    const float* __restrict__ x, const __bf16* __restrict__ W1t,
    const float* __restrict__ b1, const __bf16* __restrict__ W2t,
    const float* __restrict__ b2, const float* __restrict__ gamma,
    const float* __restrict__ beta, float* __restrict__ out) {

    __shared__ __align__(16) __bf16 Hs[4][16][136];  // per-wave private, +8 pad

    const int tid = threadIdx.x;
    const int w = tid >> 6;        // wave 0..3
    const int l = tid & 63;        // lane
    const int q = l >> 4;          // quad-of-16
    const int m = l & 15;          // within-16
    const int rowbase = blockIdx.x * 64 + w * 16;

    // per-lane column constants for the 8 16-col tiles
    float b1v[8], b2v[8], gv[8], bv[8];
#pragma unroll
    for (int t = 0; t < 8; ++t) {
        const int c = t * 16 + m;
        b1v[t] = b1[c]; b2v[t] = b2[c]; gv[t] = gamma[c]; bv[t] = beta[c];
    }

    // ---- GEMM1: H = GELU(x @ W_eff + b_eff), x fp32 -> bf16 on the fly
    f32x4 acc[8];
#pragma unroll
    for (int t = 0; t < 8; ++t) acc[t] = (f32x4)(0.0f);

    const float* xrow = x + (size_t)(rowbase + m) * D;
#pragma unroll
    for (int ks = 0; ks < 4; ++ks) {
        const float4* xp = (const float4*)(xrow + ks * 32 + q * 8);
        const float4 xa = xp[0];
        const float4 xb = xp[1];
        bf16x8 a;
        a[0] = (__bf16)xa.x; a[1] = (__bf16)xa.y; a[2] = (__bf16)xa.z; a[3] = (__bf16)xa.w;
        a[4] = (__bf16)xb.x; a[5] = (__bf16)xb.y; a[6] = (__bf16)xb.z; a[7] = (__bf16)xb.w;
#pragma unroll
        for (int t = 0; t < 8; ++t) {
            const bf16x8 bfr = *(const bf16x8*)(W1t + (t * 16 + m) * D + ks * 32 + q * 8);
            acc[t] = __builtin_amdgcn_mfma_f32_16x16x32_bf16(a, bfr, acc[t], 0, 0, 0);
        }
    }

    // bias + exact GELU, write bf16 to wave-private LDS (C-layout -> row-major)
#pragma unroll
    for (int t = 0; t < 8; ++t) {
#pragma unroll
        for (int j = 0; j < 4; ++j) {
            const float v = acc[t][j] + b1v[t];
            const float ge = 0.5f * v * (1.0f + erff(v * 0.70710678118654752f));
            Hs[w][q * 4 + j][t * 16 + m] = (__bf16)ge;
        }
    }
    __syncthreads();  // cheap; guarantees LDS write->read ordering

    // ---- GEMM2: O = H @ W_out
    f32x4 acc2[8];
#pragma unroll
    for (int t = 0; t < 8; ++t) acc2[t] = (f32x4)(0.0f);
#pragma unroll
    for (int ks = 0; ks < 4; ++ks) {
        const bf16x8 a = *(const bf16x8*)&Hs[w][m][ks * 32 + q * 8];
#pragma unroll
        for (int t = 0; t < 8; ++t) {
            const bf16x8 bfr = *(const bf16x8*)(W2t + (t * 16 + m) * D + ks * 32 + q * 8);
            acc2[t] = __builtin_amdgcn_mfma_f32_16x16x32_bf16(a, bfr, acc2[t], 0, 0, 0);
        }
    }

    // ---- bias + LayerNorm over 128 cols (rows live in 16-lane groups)
    float vsum[4] = {0.f, 0.f, 0.f, 0.f}, vsq[4] = {0.f, 0.f, 0.f, 0.f};
#pragma unroll
    for (int t = 0; t < 8; ++t) {
#pragma unroll
        for (int j = 0; j < 4; ++j) {
            const float v = acc2[t][j] + b2v[t];
            acc2[t][j] = v;
            vsum[j] += v;
            vsq[j] += v * v;
        }
    }
#pragma unroll
    for (int j = 0; j < 4; ++j) {
#pragma unroll
        for (int mask = 1; mask <= 8; mask <<= 1) {
            vsum[j] += __shfl_xor(vsum[j], mask);
            vsq[j]  += __shfl_xor(vsq[j], mask);
        }
    }
    float mu[4], rstd[4];
#pragma unroll
    for (int j = 0; j < 4; ++j) {
        mu[j] = vsum[j] * (1.0f / 128.0f);
        const float var = vsq[j] * (1.0f / 128.0f) - mu[j] * mu[j];
        rstd[j] = rsqrtf(var + 1e-5f);
    }
#pragma unroll
    for (int t = 0; t < 8; ++t) {
#pragma unroll
        for (int j = 0; j < 4; ++j) {
            const float o = (acc2[t][j] - mu[j]) * rstd[j] * gv[t] + bv[t];
            out[(size_t)(rowbase + q * 4 + j) * D + t * 16 + m] = o;
        }
    }
}

extern "C" void kernel_launch(void* const* d_in, const int* in_sizes, int n_in,
                              void* d_out, int out_size, void* d_ws, size_t ws_size,
                              hipStream_t stream) {
    const float* x     = (const float*)d_in[0];
    const float* graph = (const float*)d_in[1];
    const float* W_msg = (const float*)d_in[2];
    const float* b_msg = (const float*)d_in[3];
    const float* W_upd = (const float*)d_in[4];
    const float* b_upd = (const float*)d_in[5];
    const float* W_out = (const float*)d_in[6];
    const float* b_out = (const float*)d_in[7];
    const float* gamma = (const float*)d_in[8];
    const float* beta  = (const float*)d_in[9];
    float* out = (float*)d_out;

    char* ws = (char*)d_ws;
    float*  G2    = (float*)(ws + 0);        // 128*128 fp32 = 65536 B
    float*  b2tmp = (float*)(ws + 65536);    // 128 fp32
    float*  b_eff = (float*)(ws + 66048);    // 128 fp32
    __bf16* W1t   = (__bf16*)(ws + 66560);   // 128*128 bf16 = 32768 B
    __bf16* W2t   = (__bf16*)(ws + 99328);   // 128*128 bf16 = 32768 B

    prep1<<<128, 128, 0, stream>>>(W_msg, graph, b_msg, W_out, G2, b2tmp, W2t);
    prep2<<<128, 128, 0, stream>>>(W_upd, b_upd, G2, b2tmp, W1t, b_eff);
    fused_main<<<NROWS / 64, 256, 0, stream>>>(x, W1t, b_eff, W2t, b_out, gamma, beta, out);
}